// Round 1
// 131.690 us; speedup vs baseline: 1.0468x; 1.0468x over previous
//
#include <hip/hip_runtime.h>
#include <stdint.h>

// Dims: msa[1,S,R,M] fp32 ; left_w/right_w[M,C] ; out_w[C*C,CZ] ; out[1,R,R,CZ] fp32
#define S_DIM 128
#define R_DIM 256
#define M_DIM 256
#define C_DIM 32
#define CZ_DIM 128
#define K2_DIM 1024  // C*C

typedef _Float16 f16;
typedef _Float16 f16x4 __attribute__((ext_vector_type(4)));
typedef _Float16 f16x8 __attribute__((ext_vector_type(8)));
typedef float f32x4 __attribute__((ext_vector_type(4)));
typedef float f32x16 __attribute__((ext_vector_type(16)));

typedef const __attribute__((address_space(1))) uint32_t gu32_t;
typedef __attribute__((address_space(3))) uint32_t lu32_t;
// async 16B global->LDS DMA; LDS dest = wave-uniform base + lane*16 (linear)
#define GLOAD_LDS16(g, l) \
    __builtin_amdgcn_global_load_lds((gu32_t*)(g), (lu32_t*)(l), 16, 0, 0)

// ---------------------------------------------------------------------------
// proj (absorbs old prep): per block (r, s-half):
//   stage A: this block's 256-elem slice of wt2 (fragment-major reorder of
//            out_w; exactly 512*256 threads == CZ*K2 elements) + cooperative
//            lw/rw -> f16 transpose-stage into LDS [mc=32][c=32][j=8].
//   stage B: D = wt(32 c x 256 m) @ msa_r^T (256 m x 64 s), left & right.
// left_t is written PRE-SWIZZLED in fuse's phase-0 LDS image order
// (chunk (row*16 + ((s>>3)^(row&15)))*8 + (s&7)) so fuse stages it with
// linear global_load_lds. rt2 (stage1 A-fragment-major) unchanged.
// ---------------------------------------------------------------------------
__global__ __launch_bounds__(256, 4)
void proj_kernel(const float* __restrict__ msa, const float* __restrict__ lw,
                 const float* __restrict__ rw, const float* __restrict__ ow,
                 f16* __restrict__ left_t, f16* __restrict__ rt2,
                 f16* __restrict__ wt2) {
    __shared__ __align__(16) f16 wlT[8192];  // [mc][c][j] : frag reads are
    __shared__ __align__(16) f16 wrT[8192];  // contiguous 256B -> conflict-free

    int bid = blockIdx.x;            // 512 = 256 r * 2 s-halves
    int tid = threadIdx.x;
    int w = tid >> 6;
    int lane = tid & 63;
    int q = lane >> 4, li = lane & 15;
    int r  = bid >> 1;
    int s0 = (bid & 1) << 6;
    int s_col = s0 + w * 16 + li;

    // issue msa loads first — latency hides under stage A
    const f32x4* bp = (const f32x4*)(msa + ((size_t)s_col * R_DIM + r) * M_DIM + q * 8);
    f32x4 b[16];
#pragma unroll
    for (int ks = 0; ks < 8; ks++) { b[2 * ks] = bp[ks * 8]; b[2 * ks + 1] = bp[ks * 8 + 1]; }

    // ---- stage A: wt2 slice (old prep, one element per thread) ----
    {
        int i = bid * 256 + tid;     // in [0, CZ*K2)
        int cz = i >> 10, k2 = i & 1023;
        int c = k2 >> 5, e = k2 & 31;
        int k2p = ((e >> 2) << 7) + (c << 2) + (e & 3);
        int ntile = cz >> 5, l31o = cz & 31;
        int kk = k2p >> 4, q5o = (k2p >> 3) & 1, j = k2p & 7;
        wt2[(ntile * 64 + kk) * 512 + (l31o * 2 + q5o) * 8 + j] = (f16)ow[k2 * CZ_DIM + cz];
    }
    // ---- stage A: weight transpose-stage (coalesced fp32 reads) ----
#pragma unroll
    for (int k = 0; k < 32; k++) {
        int i = k * 256 + tid;       // i = m*32 + c
        int m = i >> 5, c = i & 31;
        int d = ((m >> 3) * 32 + c) * 8 + (m & 7);
        wlT[d] = (f16)lw[i];
        wrT[d] = (f16)rw[i];
    }
    __syncthreads();

    // ---- stage B: MFMA loop, frags from LDS ----
    f32x4 aL0 = {0,0,0,0}, aL1 = {0,0,0,0}, aR0 = {0,0,0,0}, aR1 = {0,0,0,0};
#pragma unroll
    for (int ks = 0; ks < 8; ks++) {
        f16x8 bf;
#pragma unroll
        for (int u = 0; u < 4; u++) { bf[u] = (f16)b[2*ks][u]; bf[4 + u] = (f16)b[2*ks+1][u]; }
        const f16* a0 = wlT + ((ks * 4 + q) * 32 + li) * 8;
        const f16* a1 = wrT + ((ks * 4 + q) * 32 + li) * 8;
        f16x8 al0 = *(const f16x8*)(a0);
        f16x8 al1 = *(const f16x8*)(a0 + 128);   // rows li+16
        f16x8 ar0 = *(const f16x8*)(a1);
        f16x8 ar1 = *(const f16x8*)(a1 + 128);
        aL0 = __builtin_amdgcn_mfma_f32_16x16x32_f16(al0, bf, aL0, 0, 0, 0);
        aL1 = __builtin_amdgcn_mfma_f32_16x16x32_f16(al1, bf, aL1, 0, 0, 0);
        aR0 = __builtin_amdgcn_mfma_f32_16x16x32_f16(ar0, bf, aR0, 0, 0, 0);
        aR1 = __builtin_amdgcn_mfma_f32_16x16x32_f16(ar1, bf, aR1, 0, 0, 0);
    }
    int ks_s = s_col >> 4, q5_s = (s_col >> 3) & 1, j_s = s_col & 7;
    int sbase = (r * 8 + ks_s) * 512 + q5_s * 8 + j_s;
    int rl = r & 7;
    f16* Lb = left_t + (size_t)(r >> 3) * 32768;
    int sc = s_col >> 3, sj = s_col & 7;
#pragma unroll
    for (int reg = 0; reg < 4; reg++) {
        int c0 = q * 4 + reg;                    // 0..15 ; row&15 == c0 for both rows
        int row0 = rl * 32 + c0;
        int swz = sc ^ c0;
        Lb[(row0 * 16 + swz) * 8 + sj]        = (f16)aL0[reg];
        Lb[((row0 + 16) * 16 + swz) * 8 + sj] = (f16)aL1[reg];
        rt2[sbase + c0 * 16]        = (f16)aR0[reg];
        rt2[sbase + (c0 + 16) * 16] = (f16)aR1[reg];
    }
}

// ---------------------------------------------------------------------------
// fuse_kernel v6: v5 with phase 0 replaced by async global_load_lds (left_t
// arrives pre-swizzled from proj → linear conflict-free LDS writes, no VGPR
// round-trip; DMA overlaps the afr register prefetch).
// ---------------------------------------------------------------------------
__global__ __launch_bounds__(512, 4)
void fuse_kernel(const f16* __restrict__ left_t, const f16* __restrict__ rt2,
                 const f16* __restrict__ wt2, float* __restrict__ out) {
    __shared__ __align__(16) char lds[65536];
    f16* Ls = (f16*)lds;

    int bid = blockIdx.x;        // 2048 = 32 br * 64 bt
    int br = bid >> 6, bt = bid & 63;
    int tid = threadIdx.x;
    int w = tid >> 6, lane = tid & 63;
    int q5 = lane >> 5, l31 = lane & 31, lx = lane & 15;

    const f16* Lg = left_t + (size_t)br * 32768;    // pre-swizzled LDS image

    // ---- phase 0: async stage left (8 x 16B DMA per thread) ----
#pragma unroll
    for (int it = 0; it < 8; it++) {
        GLOAD_LDS16(Lg + (size_t)(it * 512 + tid) * 8, Ls + (it * 512 + tid) * 8);
    }

    // afr prefetch (coalesced fragment-major) — overlaps the DMA
    int t_tile = w & 3, rg4 = w >> 2;
    int g = bt * 4 + t_tile;
    const f16* ap = rt2 + (size_t)g * 4096 + (l31 * 2 + q5) * 8;
    f16x8 afr[8];
#pragma unroll
    for (int ks = 0; ks < 8; ks++) afr[ks] = *(const f16x8*)(ap + ks * 512);

    __syncthreads();   // drains vmcnt → LDS stage complete

    // ---- phase 1: stage1 MFMAs (D[te][rc]) ----
    f32x16 acc[4] = {};
#pragma unroll
    for (int i = 0; i < 4; i++) {
        const f16* bbase = Ls + ((rg4 * 4 + i) * 32 + l31) * 128;
#pragma unroll
        for (int ks = 0; ks < 8; ks++) {
            f16x8 bfr = *(const f16x8*)(bbase + (((2 * ks + q5) ^ lx) << 3));
            acc[i] = __builtin_amdgcn_mfma_f32_32x32x16_f16(afr[ks], bfr, acc[i], 0, 0, 0);
        }
    }

    // ---- W group 0: issue pre-barrier (hidden by phase 2 + barrier) ----
    int ntile = w & 3, kh = w >> 2;
    const f16* wbase = wt2 + (size_t)(ntile * 64 + kh * 32) * 512 + (l31 * 2 + q5) * 8;
    f16x8 wfg[8][4];
#pragma unroll
    for (int u = 0; u < 4; u++) wfg[0][u] = *(const f16x8*)(wbase + u * 512);

    __syncthreads();   // protects LDS overlay (phase2 writes over Ls)

    // ---- phase 2: write outer to LDS ----
    int chc = l31 >> 1, bsub = 8 * (l31 & 1);
#pragma unroll
    for (int i = 0; i < 4; i++) {
        int p = (rg4 * 4 + i) * 4 + t_tile;         // pair row 0..31
        char* prow = lds + p * 2048;
#pragma unroll
        for (int rg = 0; rg < 4; rg++) {
            int ch = (2 * rg + q5) * 16 + chc;
            int phys = (ch + p) & 127;
            f16x4 h = {(f16)acc[i][4 * rg], (f16)acc[i][4 * rg + 1],
                       (f16)acc[i][4 * rg + 2], (f16)acc[i][4 * rg + 3]};
            *(f16x4*)(prow + phys * 16 + bsub) = h;
        }
    }
    __syncthreads();

    // ---- phase 3: stage2, fully unrolled, 3-deep W ring + 2-deep af ring ----
    const char* lbase = lds + l31 * 2048;           // p = l31 (2048-aligned rows)
    int base = 64 * kh + q5 + l31;                  // k-chunk index before wrap
    f16x8 afg[8][4];
    f32x16 accA = {}, accB = {};
#pragma unroll
    for (int gg = 0; gg < 8; gg++) {
        if (gg == 0) {
            // fill rings: W groups 1,2 ; af groups 0,1
#pragma unroll
            for (int u = 0; u < 4; u++) wfg[1][u] = *(const f16x8*)(wbase + (4 + u) * 512);
#pragma unroll
            for (int u = 0; u < 4; u++) wfg[2][u] = *(const f16x8*)(wbase + (8 + u) * 512);
#pragma unroll
            for (int u = 0; u < 4; u++)
                afg[0][u] = *(const f16x8*)(lbase + (((base + 2 * u) & 127) << 4));
#pragma unroll
            for (int u = 0; u < 4; u++)
                afg[1][u] = *(const f16x8*)(lbase + (((base + 8 + 2 * u) & 127) << 4));
        } else {
            if (gg + 2 < 8) {
#pragma unroll
                for (int u = 0; u < 4; u++)
                    wfg[gg + 2][u] = *(const f16x8*)(wbase + ((gg + 2) * 4 + u) * 512);
            }
            if (gg + 1 < 8) {
#pragma unroll
                for (int u = 0; u < 4; u++)
                    afg[gg + 1][u] = *(const f16x8*)(lbase + (((base + (gg + 1) * 8 + 2 * u) & 127) << 4));
            }
        }
        accA = __builtin_amdgcn_mfma_f32_32x32x16_f16(afg[gg][0], wfg[gg][0], accA, 0, 0, 0);
        accB = __builtin_amdgcn_mfma_f32_32x32x16_f16(afg[gg][1], wfg[gg][1], accB, 0, 0, 0);
        accA = __builtin_amdgcn_mfma_f32_32x32x16_f16(afg[gg][2], wfg[gg][2], accA, 0, 0, 0);
        accB = __builtin_amdgcn_mfma_f32_32x32x16_f16(afg[gg][3], wfg[gg][3], accB, 0, 0, 0);
    }
    f32x16 acc2;
#pragma unroll
    for (int v = 0; v < 16; v++) acc2[v] = accA[v] + accB[v];
    __syncthreads();

    // ---- k-reduction: wave w+4 -> LDS, wave w adds ----
    if (w >= 4) {
        char* rb = lds + (w - 4) * 4096 + lane * 64;
#pragma unroll
        for (int u = 0; u < 4; u++) {
            f32x4 part = {acc2[4 * u], acc2[4 * u + 1], acc2[4 * u + 2], acc2[4 * u + 3]};
            *(f32x4*)(rb + u * 16) = part;
        }
    }
    __syncthreads();
    if (w < 4) {
        const char* rb = lds + w * 4096 + lane * 64;
#pragma unroll
        for (int u = 0; u < 4; u++) {
            f32x4 part = *(const f32x4*)(rb + u * 16);
#pragma unroll
            for (int v = 0; v < 4; v++) acc2[4 * u + v] += part[v];
        }
        // store: D row = p = (reg&3)+8*(reg>>2)+4*q5 ; col = cz = w*32 + l31
        int r0 = br * 8, t0 = bt * 4, cz = w * 32 + l31;
#pragma unroll
        for (int reg = 0; reg < 16; reg++) {
            int p = (reg & 3) + 8 * (reg >> 2) + 4 * q5;
            out[((size_t)((r0 + (p >> 2)) * R_DIM + t0 + (p & 3))) * CZ_DIM + cz] = acc2[reg];
        }
    }
}

// ---------------------------------------------------------------------------
extern "C" void kernel_launch(void* const* d_in, const int* in_sizes, int n_in,
                              void* d_out, int out_size, void* d_ws, size_t ws_size,
                              hipStream_t stream) {
    const float* msa = (const float*)d_in[0];
    const float* lw  = (const float*)d_in[1];
    const float* rw  = (const float*)d_in[2];
    const float* ow  = (const float*)d_in[3];
    char* ws = (char*)d_ws;
    f16* left_t = (f16*)(ws);                                   // 2 MB (pre-swizzled)
    f16* rt2    = (f16*)(ws + (size_t)2 * 1024 * 1024);         // 2 MB
    f16* wt2    = (f16*)(ws + (size_t)4 * 1024 * 1024);         // 256 KB
    float* out  = (float*)d_out;

    proj_kernel<<<dim3(512), dim3(256), 0, stream>>>(msa, lw, rw, ow, left_t, rt2, wt2);
    fuse_kernel<<<dim3(2048), dim3(512), 0, stream>>>(left_t, rt2, wt2, out);
}